// Round 9
// baseline (637.680 us; speedup 1.0000x reference)
//
#include <hip/hip_runtime.h>

// ---------------------------------------------------------------------------
// GCN forward, CSR-sorted aggregation (no atomics in hot path):
//   build: XCD-partitioned deg count -> scan(+dinv) -> XCD-partitioned fill(+wgt)
//   W prep: one kernel splits all 3 fp32 W -> bf16 hi/lo in MFMA B-frag order
//   gemm1: x(fp32) x W1 -> A16a (bf16-split MFMA, LDS-free)
//   fused l=2,3: per-wave agg (fp16 gather, fp32 acc) -> LDS strip -> relu ->
//                bf16-split MFMA x W(l) -> A16 ping-pong  (B matrix eliminated)
//   head: agg + relu + lin_w dot -> nodeval -> per-graph segmented reduce
// ---------------------------------------------------------------------------

typedef __attribute__((ext_vector_type(8))) short bf16x8;
typedef __attribute__((ext_vector_type(4))) float f32x4;
typedef __attribute__((ext_vector_type(8))) _Float16 half8;

__device__ __forceinline__ unsigned short f32_to_bf16_rne(float f) {
    unsigned u = __float_as_uint(f);
    unsigned r = u + 0x7FFF + ((u >> 16) & 1);
    return (unsigned short)(r >> 16);
}
__device__ __forceinline__ float bf16_to_f32(unsigned short h) {
    return __uint_as_float(((unsigned)h) << 16);
}

// XCD-partitioned degree count (8 blocks round-robin -> 8 XCDs share each chunk)
__global__ __launch_bounds__(256) void count_deg_kernel(const int* __restrict__ col,
                                                        int* __restrict__ deg,
                                                        int E, int partSize) {
    const int p = blockIdx.x & 7;
    const int e = (blockIdx.x >> 3) * 256 + threadIdx.x;
    if (e >= E) return;
    int c = col[e];
    if (c / partSize == p) atomicAdd(&deg[c], 1);
}

// per-block exclusive scan of deg (1024/block) -> rowptr; also dinv = rsqrt(deg+1)
__global__ __launch_bounds__(256) void scan1_kernel(const int* __restrict__ deg,
                                                    int* __restrict__ rowptr,
                                                    float* __restrict__ dinv,
                                                    int* __restrict__ blockSums, int N) {
    __shared__ int ts[256];
    const int t = threadIdx.x;
    const int base = blockIdx.x * 1024 + t * 4;
    int v0 = 0, v1 = 0, v2 = 0, v3 = 0;
    if (base + 3 < N) {
        int4 v = *(const int4*)&deg[base];
        v0 = v.x; v1 = v.y; v2 = v.z; v3 = v.w;
    } else {
        if (base + 0 < N) v0 = deg[base + 0];
        if (base + 1 < N) v1 = deg[base + 1];
        if (base + 2 < N) v2 = deg[base + 2];
        if (base + 3 < N) v3 = deg[base + 3];
    }
    if (base + 0 < N) dinv[base + 0] = 1.0f / sqrtf((float)v0 + 1.0f);
    if (base + 1 < N) dinv[base + 1] = 1.0f / sqrtf((float)v1 + 1.0f);
    if (base + 2 < N) dinv[base + 2] = 1.0f / sqrtf((float)v2 + 1.0f);
    if (base + 3 < N) dinv[base + 3] = 1.0f / sqrtf((float)v3 + 1.0f);
    const int tot = v0 + v1 + v2 + v3;
    ts[t] = tot;
    __syncthreads();
    for (int off = 1; off < 256; off <<= 1) {
        int add = (t >= off) ? ts[t - off] : 0;
        __syncthreads();
        ts[t] += add;
        __syncthreads();
    }
    const int excl = ts[t] - tot;
    if (base + 0 < N) rowptr[base + 0] = excl;
    if (base + 1 < N) rowptr[base + 1] = excl + v0;
    if (base + 2 < N) rowptr[base + 2] = excl + v0 + v1;
    if (base + 3 < N) rowptr[base + 3] = excl + v0 + v1 + v2;
    if (t == 255) blockSums[blockIdx.x] = ts[255];
}

__global__ __launch_bounds__(128) void scan2_kernel(const int* __restrict__ blockSums,
                                                    int* __restrict__ blockOffs, int B) {
    __shared__ int ts[128];
    const int t = threadIdx.x;
    ts[t] = (t < B) ? blockSums[t] : 0;
    __syncthreads();
    for (int off = 1; off < 128; off <<= 1) {
        int add = (t >= off) ? ts[t - off] : 0;
        __syncthreads();
        ts[t] += add;
        __syncthreads();
    }
    if (t < B) blockOffs[t] = ts[t];
}

__global__ __launch_bounds__(256) void scan3_kernel(int* __restrict__ rowptr,
                                                    const int* __restrict__ blockOffs, int N) {
    int i = blockIdx.x * 256 + threadIdx.x;
    if (i >= N) return;
    int b = i >> 10;
    if (b > 0) rowptr[i] += blockOffs[b - 1];
}

// XCD-partitioned counting-sort fill (rowptr-shift trick) + per-edge weight
__global__ __launch_bounds__(256) void fill_kernel(const int* __restrict__ ei,
                                                   const float* __restrict__ dinv,
                                                   int* __restrict__ rowptr,
                                                   int* __restrict__ src_sorted,
                                                   float* __restrict__ wgt,
                                                   int E, int partSize) {
    const int p = blockIdx.x & 7;
    const int e = (blockIdx.x >> 3) * 256 + threadIdx.x;
    if (e >= E) return;
    int c = ei[E + e];
    if (c / partSize != p) return;
    int r = ei[e];
    int pos = atomicAdd(&rowptr[c], 1);
    src_sorted[pos] = r;
    wgt[pos] = dinv[r];
}

// split all three W[128][128] fp32 -> bf16 hi/lo in MFMA B-fragment order:
// idx = ((c*8+t)*64+lane)*8+j <-> W[k][n], k=c*32+(lane>>4)*8+j, n=t*16+(lane&15)
__global__ __launch_bounds__(256) void wsplit_kernel(const float* __restrict__ W1,
                                                     const float* __restrict__ W2,
                                                     const float* __restrict__ W3,
                                                     unsigned short* __restrict__ Wfrag) {
    int layer = blockIdx.x >> 6;
    const float* W = (layer == 0) ? W1 : (layer == 1) ? W2 : W3;
    unsigned short* Whi = Wfrag + layer * 32768;
    unsigned short* Wlo = Whi + 16384;
    int i = (blockIdx.x & 63) * 256 + threadIdx.x;   // 16384 per layer
    int j = i & 7;
    int l = (i >> 3) & 63;
    int t = (i >> 9) & 7;
    int c = i >> 12;
    int k = c * 32 + (l >> 4) * 8 + j;
    int n = t * 16 + (l & 15);
    float v = W[k * 128 + n];
    unsigned short hi = f32_to_bf16_rne(v);
    Whi[i] = hi;
    Wlo[i] = f32_to_bf16_rne(v - bf16_to_f32(hi));
}

// T16 = fp16( act(H_f32) @ W ) via bf16-split MFMA; B-frags from L2-resident global.
__global__ __launch_bounds__(256) void gemm_mfma_kernel(const float* __restrict__ H,
                                                        const unsigned short* __restrict__ Whi,
                                                        const unsigned short* __restrict__ Wlo,
                                                        _Float16* __restrict__ T16,
                                                        int N) {
    const int tid = threadIdx.x;
    const int wv = tid >> 6;
    const int lane = tid & 63;
    const int r0 = blockIdx.x * 64 + wv * 16;
    const int mrow = lane & 15;
    const int kq = lane >> 4;
    const int grow = r0 + mrow;
    const bool rok = grow < N;

    f32x4 acc[8];
    #pragma unroll
    for (int t = 0; t < 8; ++t) acc[t] = (f32x4){0.f, 0.f, 0.f, 0.f};

    #pragma unroll
    for (int c = 0; c < 4; ++c) {
        float av[8];
        if (rok) {
            const float4* Hp = (const float4*)(H + (size_t)grow * 128 + c * 32 + kq * 8);
            float4 a0 = Hp[0], a1 = Hp[1];
            av[0] = a0.x; av[1] = a0.y; av[2] = a0.z; av[3] = a0.w;
            av[4] = a1.x; av[5] = a1.y; av[6] = a1.z; av[7] = a1.w;
        } else {
            #pragma unroll
            for (int j = 0; j < 8; ++j) av[j] = 0.f;
        }
        bf16x8 ahi, alo;
        #pragma unroll
        for (int j = 0; j < 8; ++j) {
            float v = av[j];
            unsigned short h = f32_to_bf16_rne(v);
            unsigned short l = f32_to_bf16_rne(v - bf16_to_f32(h));
            ahi[j] = (short)h;
            alo[j] = (short)l;
        }
        #pragma unroll
        for (int t = 0; t < 8; ++t) {
            const int fidx = (((c * 8 + t) * 64) + lane) * 8;
            bf16x8 wh = *(const bf16x8*)&Whi[fidx];
            bf16x8 wl = *(const bf16x8*)&Wlo[fidx];
            acc[t] = __builtin_amdgcn_mfma_f32_16x16x32_bf16(ahi, wh, acc[t], 0, 0, 0);
            acc[t] = __builtin_amdgcn_mfma_f32_16x16x32_bf16(ahi, wl, acc[t], 0, 0, 0);
            acc[t] = __builtin_amdgcn_mfma_f32_16x16x32_bf16(alo, wh, acc[t], 0, 0, 0);
        }
    }
    #pragma unroll
    for (int r = 0; r < 4; ++r) {
        int orow = r0 + kq * 4 + r;
        if (orow < N) {
            _Float16* Tp = T16 + (size_t)orow * 128 + mrow;
            #pragma unroll
            for (int t = 0; t < 8; ++t) Tp[t * 16] = (_Float16)acc[t][r];
        }
    }
}

// Fused agg + next-layer GEMM. Each wave aggregates its 16 MFMA rows into a
// wave-private LDS strip (fp32, pad 132 -> mild conflicts), then relu +
// bf16-split + MFMA x W -> Aout fp16. No barrier needed (wave-local LDS).
__global__ __launch_bounds__(256) void fused_agg_gemm_kernel(
        const int* __restrict__ rowptr, const int* __restrict__ src,
        const float* __restrict__ wgt, const float* __restrict__ dinv,
        const _Float16* __restrict__ Ain, const float* __restrict__ bias,
        const unsigned short* __restrict__ Whi, const unsigned short* __restrict__ Wlo,
        _Float16* __restrict__ Aout, int N) {
    __shared__ float hs[64 * 132];
    const int tid = threadIdx.x;
    const int wv = tid >> 6;
    const int lane = tid & 63;
    const int g = lane >> 4;           // edge subgroup 0..3
    const int q = lane & 15;           // 16B slot (8 halves)
    const int nodeBase = blockIdx.x * 64 + wv * 16;
    const half8* A8 = (const half8*)Ain;

    // ---- phase 1: aggregate 16 nodes (fp16 gather, fp32 acc) ----
    for (int i = 0; i < 16; ++i) {
        const int w = nodeBase + i;
        if (w >= N) break;
        const int beg = (w > 0) ? rowptr[w - 1] : 0;
        const int end = rowptr[w];
        const float dn = dinv[w];
        float4 a0 = make_float4(0.f, 0.f, 0.f, 0.f);
        float4 a1 = make_float4(0.f, 0.f, 0.f, 0.f);
        for (int e = beg + g; e < end; e += 4) {
            int s = src[e];
            float nrm = dn * wgt[e];
            half8 v = A8[(size_t)s * 16 + q];
            a0.x = fmaf(nrm, (float)v[0], a0.x); a0.y = fmaf(nrm, (float)v[1], a0.y);
            a0.z = fmaf(nrm, (float)v[2], a0.z); a0.w = fmaf(nrm, (float)v[3], a0.w);
            a1.x = fmaf(nrm, (float)v[4], a1.x); a1.y = fmaf(nrm, (float)v[5], a1.y);
            a1.z = fmaf(nrm, (float)v[6], a1.z); a1.w = fmaf(nrm, (float)v[7], a1.w);
        }
        a0.x += __shfl_xor(a0.x, 16); a0.y += __shfl_xor(a0.y, 16);
        a0.z += __shfl_xor(a0.z, 16); a0.w += __shfl_xor(a0.w, 16);
        a1.x += __shfl_xor(a1.x, 16); a1.y += __shfl_xor(a1.y, 16);
        a1.z += __shfl_xor(a1.z, 16); a1.w += __shfl_xor(a1.w, 16);
        a0.x += __shfl_xor(a0.x, 32); a0.y += __shfl_xor(a0.y, 32);
        a0.z += __shfl_xor(a0.z, 32); a0.w += __shfl_xor(a0.w, 32);
        a1.x += __shfl_xor(a1.x, 32); a1.y += __shfl_xor(a1.y, 32);
        a1.z += __shfl_xor(a1.z, 32); a1.w += __shfl_xor(a1.w, 32);
        if (g == 0) {
            half8 sv = A8[(size_t)w * 16 + q];
            float4 b0 = ((const float4*)bias)[q * 2];
            float4 b1 = ((const float4*)bias)[q * 2 + 1];
            float d2 = dn * dn;
            a0.x = fmaf(d2, (float)sv[0], a0.x + b0.x);
            a0.y = fmaf(d2, (float)sv[1], a0.y + b0.y);
            a0.z = fmaf(d2, (float)sv[2], a0.z + b0.z);
            a0.w = fmaf(d2, (float)sv[3], a0.w + b0.w);
            a1.x = fmaf(d2, (float)sv[4], a1.x + b1.x);
            a1.y = fmaf(d2, (float)sv[5], a1.y + b1.y);
            a1.z = fmaf(d2, (float)sv[6], a1.z + b1.z);
            a1.w = fmaf(d2, (float)sv[7], a1.w + b1.w);
            *(float4*)&hs[(wv * 16 + i) * 132 + q * 8]     = a0;
            *(float4*)&hs[(wv * 16 + i) * 132 + q * 8 + 4] = a1;
        }
    }
    // wave-local LDS: compiler's lgkmcnt ordering suffices; no __syncthreads

    // ---- phase 2: relu + bf16-split MFMA over this wave's 16 rows ----
    const int mrow = lane & 15;
    const int kq = lane >> 4;
    const int grow = nodeBase + mrow;
    const bool rok = grow < N;

    f32x4 acc[8];
    #pragma unroll
    for (int t = 0; t < 8; ++t) acc[t] = (f32x4){0.f, 0.f, 0.f, 0.f};

    #pragma unroll
    for (int c = 0; c < 4; ++c) {
        float av[8];
        if (rok) {
            const float* hp = &hs[(wv * 16 + mrow) * 132 + c * 32 + kq * 8];
            float4 a0 = *(const float4*)hp;
            float4 a1 = *(const float4*)(hp + 4);
            av[0] = a0.x; av[1] = a0.y; av[2] = a0.z; av[3] = a0.w;
            av[4] = a1.x; av[5] = a1.y; av[6] = a1.z; av[7] = a1.w;
        } else {
            #pragma unroll
            for (int j = 0; j < 8; ++j) av[j] = 0.f;
        }
        bf16x8 ahi, alo;
        #pragma unroll
        for (int j = 0; j < 8; ++j) {
            float v = fmaxf(av[j], 0.f);   // relu
            unsigned short h = f32_to_bf16_rne(v);
            unsigned short l = f32_to_bf16_rne(v - bf16_to_f32(h));
            ahi[j] = (short)h;
            alo[j] = (short)l;
        }
        #pragma unroll
        for (int t = 0; t < 8; ++t) {
            const int fidx = (((c * 8 + t) * 64) + lane) * 8;
            bf16x8 wh = *(const bf16x8*)&Whi[fidx];
            bf16x8 wl = *(const bf16x8*)&Wlo[fidx];
            acc[t] = __builtin_amdgcn_mfma_f32_16x16x32_bf16(ahi, wh, acc[t], 0, 0, 0);
            acc[t] = __builtin_amdgcn_mfma_f32_16x16x32_bf16(ahi, wl, acc[t], 0, 0, 0);
            acc[t] = __builtin_amdgcn_mfma_f32_16x16x32_bf16(alo, wh, acc[t], 0, 0, 0);
        }
    }
    #pragma unroll
    for (int r = 0; r < 4; ++r) {
        int orow = nodeBase + kq * 4 + r;
        if (orow < N) {
            _Float16* Tp = Aout + (size_t)orow * 128 + mrow;
            #pragma unroll
            for (int t = 0; t < 8; ++t) Tp[t * 16] = (_Float16)acc[t][r];
        }
    }
}

// layer-3 head: one wave/node agg, then nodeval[n] = dot(relu(row), lin_w)
__global__ __launch_bounds__(256) void agg_head_kernel(const int* __restrict__ rowptr,
                                                       const int* __restrict__ src,
                                                       const float* __restrict__ wgt,
                                                       const float* __restrict__ dinv,
                                                       const _Float16* __restrict__ A16,
                                                       const float* __restrict__ bias,
                                                       const float* __restrict__ lin_w,
                                                       float* __restrict__ nodeval, int N) {
    int w = (blockIdx.x * 256 + threadIdx.x) >> 6;
    if (w >= N) return;
    const int lane = threadIdx.x & 63;
    const int g = lane >> 4;
    const int q = lane & 15;
    const int beg = (w > 0) ? rowptr[w - 1] : 0;
    const int end = rowptr[w];
    const float dn = dinv[w];
    const half8* A8 = (const half8*)A16;

    float4 a0 = make_float4(0.f, 0.f, 0.f, 0.f);
    float4 a1 = make_float4(0.f, 0.f, 0.f, 0.f);
    for (int e = beg + g; e < end; e += 4) {
        int s = src[e];
        float nrm = dn * wgt[e];
        half8 v = A8[(size_t)s * 16 + q];
        a0.x = fmaf(nrm, (float)v[0], a0.x); a0.y = fmaf(nrm, (float)v[1], a0.y);
        a0.z = fmaf(nrm, (float)v[2], a0.z); a0.w = fmaf(nrm, (float)v[3], a0.w);
        a1.x = fmaf(nrm, (float)v[4], a1.x); a1.y = fmaf(nrm, (float)v[5], a1.y);
        a1.z = fmaf(nrm, (float)v[6], a1.z); a1.w = fmaf(nrm, (float)v[7], a1.w);
    }
    a0.x += __shfl_xor(a0.x, 16); a0.y += __shfl_xor(a0.y, 16);
    a0.z += __shfl_xor(a0.z, 16); a0.w += __shfl_xor(a0.w, 16);
    a1.x += __shfl_xor(a1.x, 16); a1.y += __shfl_xor(a1.y, 16);
    a1.z += __shfl_xor(a1.z, 16); a1.w += __shfl_xor(a1.w, 16);
    a0.x += __shfl_xor(a0.x, 32); a0.y += __shfl_xor(a0.y, 32);
    a0.z += __shfl_xor(a0.z, 32); a0.w += __shfl_xor(a0.w, 32);
    a1.x += __shfl_xor(a1.x, 32); a1.y += __shfl_xor(a1.y, 32);
    a1.z += __shfl_xor(a1.z, 32); a1.w += __shfl_xor(a1.w, 32);

    if (g == 0) {
        half8 sv = A8[(size_t)w * 16 + q];
        float4 b0 = ((const float4*)bias)[q * 2];
        float4 b1 = ((const float4*)bias)[q * 2 + 1];
        float d2 = dn * dn;
        a0.x = fmaf(d2, (float)sv[0], a0.x + b0.x);
        a0.y = fmaf(d2, (float)sv[1], a0.y + b0.y);
        a0.z = fmaf(d2, (float)sv[2], a0.z + b0.z);
        a0.w = fmaf(d2, (float)sv[3], a0.w + b0.w);
        a1.x = fmaf(d2, (float)sv[4], a1.x + b1.x);
        a1.y = fmaf(d2, (float)sv[5], a1.y + b1.y);
        a1.z = fmaf(d2, (float)sv[6], a1.z + b1.z);
        a1.w = fmaf(d2, (float)sv[7], a1.w + b1.w);
        float4 w0 = ((const float4*)lin_w)[q * 2];
        float4 w1 = ((const float4*)lin_w)[q * 2 + 1];
        float s = fmaxf(a0.x, 0.f) * w0.x + fmaxf(a0.y, 0.f) * w0.y
                + fmaxf(a0.z, 0.f) * w0.z + fmaxf(a0.w, 0.f) * w0.w
                + fmaxf(a1.x, 0.f) * w1.x + fmaxf(a1.y, 0.f) * w1.y
                + fmaxf(a1.z, 0.f) * w1.z + fmaxf(a1.w, 0.f) * w1.w;
        s += __shfl_xor(s, 1);
        s += __shfl_xor(s, 2);
        s += __shfl_xor(s, 4);
        s += __shfl_xor(s, 8);
        if (q == 0) nodeval[w] = s;
    }
}

__device__ __forceinline__ int lower_bound_dev(const int* __restrict__ a, int n, int key) {
    int lo = 0, hi = n;
    while (lo < hi) {
        int mid = (lo + hi) >> 1;
        if (a[mid] < key) lo = mid + 1; else hi = mid;
    }
    return lo;
}

// one block per graph: out[g] = mean(nodeval[lo:hi]) + lin_b  (batch is sorted)
__global__ __launch_bounds__(256) void segreduce_kernel(const float* __restrict__ nodeval,
                                                        const int* __restrict__ batch,
                                                        const float* __restrict__ lin_b,
                                                        float* __restrict__ out, int N) {
    const int g = blockIdx.x;
    const int lo = lower_bound_dev(batch, N, g);
    const int hi = lower_bound_dev(batch, N, g + 1);
    float acc = 0.f;
    for (int n = lo + threadIdx.x; n < hi; n += 256) acc += nodeval[n];
    __shared__ float red[256];
    red[threadIdx.x] = acc;
    __syncthreads();
    for (int s = 128; s > 0; s >>= 1) {
        if (threadIdx.x < s) red[threadIdx.x] += red[threadIdx.x + s];
        __syncthreads();
    }
    if (threadIdx.x == 0) {
        float cnt = (float)(hi - lo);
        out[g] = red[0] / fmaxf(cnt, 1.0f) + lin_b[0];
    }
}

extern "C" void kernel_launch(void* const* d_in, const int* in_sizes, int n_in,
                              void* d_out, int out_size, void* d_ws, size_t ws_size,
                              hipStream_t stream) {
    const float* x     = (const float*)d_in[0];
    const int*   ei    = (const int*)d_in[1];    // [2,E]: rows then cols
    const int*   batch = (const int*)d_in[2];
    const float* W1    = (const float*)d_in[3];
    const float* b1    = (const float*)d_in[4];
    const float* W2    = (const float*)d_in[5];
    const float* b2    = (const float*)d_in[6];
    const float* W3    = (const float*)d_in[7];
    const float* b3    = (const float*)d_in[8];
    const float* lin_w = (const float*)d_in[9];
    const float* lin_b = (const float*)d_in[10];
    float* out = (float*)d_out;

    const int N = in_sizes[0] / 128;
    const int E = in_sizes[1] / 2;
    const int nBlk = (N + 1023) / 1024;
    const int partSize = (N + 7) / 8;            // XCD destination partition
    const int eChunks = (E + 255) / 256;

    // workspace: A16a | A16b | deg | dinv | rowptr | src | wgt | scan | nodeval | Wfrag
    _Float16* A16a   = (_Float16*)d_ws;
    _Float16* A16b   = A16a + (size_t)N * 128;
    int*   deg       = (int*)(A16b + (size_t)N * 128);
    float* dinv      = (float*)(deg + N);
    int*   rowptr    = (int*)(dinv + N);
    int*   src_srt   = rowptr + N;
    float* wgt       = (float*)(src_srt + E);
    int*   blockSums = (int*)(wgt + E);
    int*   blockOffs = blockSums + 256;
    float* nodeval   = (float*)(blockOffs + 256);
    unsigned short* Wfrag = (unsigned short*)(nodeval + N);  // 3 x (hi|lo) x 16384

    // ---- CSR build ----
    hipMemsetAsync(deg, 0, (size_t)N * sizeof(int), stream);
    count_deg_kernel<<<8 * eChunks, 256, 0, stream>>>(ei + E, deg, E, partSize);
    scan1_kernel<<<nBlk, 256, 0, stream>>>(deg, rowptr, dinv, blockSums, N);
    scan2_kernel<<<1, 128, 0, stream>>>(blockSums, blockOffs, nBlk);
    scan3_kernel<<<(N + 255) / 256, 256, 0, stream>>>(rowptr, blockOffs, N);
    fill_kernel<<<8 * eChunks, 256, 0, stream>>>(ei, dinv, rowptr, src_srt, wgt,
                                                 E, partSize);
    wsplit_kernel<<<192, 256, 0, stream>>>(W1, W2, W3, Wfrag);

    const int gBlocks = (N + 63) / 64;
    const int aBlocks = ((size_t)N * 64 + 255) / 256;
    // layer 1 linear: x @ W1 -> A16a
    gemm_mfma_kernel<<<gBlocks, 256, 0, stream>>>(x, Wfrag, Wfrag + 16384, A16a, N);
    // fused: agg(A16a)+b1, relu, @W2 -> A16b ; agg(A16b)+b2, relu, @W3 -> A16a
    fused_agg_gemm_kernel<<<gBlocks, 256, 0, stream>>>(rowptr, src_srt, wgt, dinv,
        A16a, b1, Wfrag + 32768, Wfrag + 32768 + 16384, A16b, N);
    fused_agg_gemm_kernel<<<gBlocks, 256, 0, stream>>>(rowptr, src_srt, wgt, dinv,
        A16b, b2, Wfrag + 65536, Wfrag + 65536 + 16384, A16a, N);
    // head: agg(A16a)+b3, relu, dot lin_w -> nodeval
    agg_head_kernel<<<aBlocks, 256, 0, stream>>>(rowptr, src_srt, wgt, dinv,
                                                 A16a, b3, lin_w, nodeval, N);
    segreduce_kernel<<<64, 256, 0, stream>>>(nodeval, batch, lin_b, out, N);
}

// Round 10
// 553.166 us; speedup vs baseline: 1.1528x; 1.1528x over previous
//
#include <hip/hip_runtime.h>

// ---------------------------------------------------------------------------
// GCN forward (R8 structure + build consolidation + 8-edge-MLP agg):
//   build: XCD-partitioned deg count -> scan(+dinv) -> XCD-partitioned fill(+wgt)
//   W prep: one kernel splits all 3 fp32 W -> bf16 hi/lo in MFMA B-frag order
//   3x: GEMM (bf16-split MFMA, LDS-free, relu-on-load) -> A16 fp16
//       agg (fp16 gather, 8 edges in flight, fp32 acc) -> B fp32 (L2-resident)
//   head: agg + relu + lin_w dot -> nodeval -> per-graph segmented reduce
// ---------------------------------------------------------------------------

typedef __attribute__((ext_vector_type(8))) short bf16x8;
typedef __attribute__((ext_vector_type(4))) float f32x4;
typedef __attribute__((ext_vector_type(8))) _Float16 half8;

__device__ __forceinline__ unsigned short f32_to_bf16_rne(float f) {
    unsigned u = __float_as_uint(f);
    unsigned r = u + 0x7FFF + ((u >> 16) & 1);
    return (unsigned short)(r >> 16);
}
__device__ __forceinline__ float bf16_to_f32(unsigned short h) {
    return __uint_as_float(((unsigned)h) << 16);
}

// XCD-partitioned degree count (8 blocks round-robin -> 8 XCDs share each chunk)
__global__ __launch_bounds__(256) void count_deg_kernel(const int* __restrict__ col,
                                                        int* __restrict__ deg,
                                                        int E, int partSize) {
    const int p = blockIdx.x & 7;
    const int e = (blockIdx.x >> 3) * 256 + threadIdx.x;
    if (e >= E) return;
    int c = col[e];
    if (c / partSize == p) atomicAdd(&deg[c], 1);
}

// per-block exclusive scan of deg (1024/block) -> rowptr; also dinv = rsqrt(deg+1)
__global__ __launch_bounds__(256) void scan1_kernel(const int* __restrict__ deg,
                                                    int* __restrict__ rowptr,
                                                    float* __restrict__ dinv,
                                                    int* __restrict__ blockSums, int N) {
    __shared__ int ts[256];
    const int t = threadIdx.x;
    const int base = blockIdx.x * 1024 + t * 4;
    int v0 = 0, v1 = 0, v2 = 0, v3 = 0;
    if (base + 3 < N) {
        int4 v = *(const int4*)&deg[base];
        v0 = v.x; v1 = v.y; v2 = v.z; v3 = v.w;
    } else {
        if (base + 0 < N) v0 = deg[base + 0];
        if (base + 1 < N) v1 = deg[base + 1];
        if (base + 2 < N) v2 = deg[base + 2];
        if (base + 3 < N) v3 = deg[base + 3];
    }
    if (base + 0 < N) dinv[base + 0] = 1.0f / sqrtf((float)v0 + 1.0f);
    if (base + 1 < N) dinv[base + 1] = 1.0f / sqrtf((float)v1 + 1.0f);
    if (base + 2 < N) dinv[base + 2] = 1.0f / sqrtf((float)v2 + 1.0f);
    if (base + 3 < N) dinv[base + 3] = 1.0f / sqrtf((float)v3 + 1.0f);
    const int tot = v0 + v1 + v2 + v3;
    ts[t] = tot;
    __syncthreads();
    for (int off = 1; off < 256; off <<= 1) {
        int add = (t >= off) ? ts[t - off] : 0;
        __syncthreads();
        ts[t] += add;
        __syncthreads();
    }
    const int excl = ts[t] - tot;
    if (base + 0 < N) rowptr[base + 0] = excl;
    if (base + 1 < N) rowptr[base + 1] = excl + v0;
    if (base + 2 < N) rowptr[base + 2] = excl + v0 + v1;
    if (base + 3 < N) rowptr[base + 3] = excl + v0 + v1 + v2;
    if (t == 255) blockSums[blockIdx.x] = ts[255];
}

__global__ __launch_bounds__(128) void scan2_kernel(const int* __restrict__ blockSums,
                                                    int* __restrict__ blockOffs, int B) {
    __shared__ int ts[128];
    const int t = threadIdx.x;
    ts[t] = (t < B) ? blockSums[t] : 0;
    __syncthreads();
    for (int off = 1; off < 128; off <<= 1) {
        int add = (t >= off) ? ts[t - off] : 0;
        __syncthreads();
        ts[t] += add;
        __syncthreads();
    }
    if (t < B) blockOffs[t] = ts[t];
}

__global__ __launch_bounds__(256) void scan3_kernel(int* __restrict__ rowptr,
                                                    const int* __restrict__ blockOffs, int N) {
    int i = blockIdx.x * 256 + threadIdx.x;
    if (i >= N) return;
    int b = i >> 10;
    if (b > 0) rowptr[i] += blockOffs[b - 1];
}

// XCD-partitioned counting-sort fill (rowptr-shift trick) + per-edge weight
__global__ __launch_bounds__(256) void fill_kernel(const int* __restrict__ ei,
                                                   const float* __restrict__ dinv,
                                                   int* __restrict__ rowptr,
                                                   int* __restrict__ src_sorted,
                                                   float* __restrict__ wgt,
                                                   int E, int partSize) {
    const int p = blockIdx.x & 7;
    const int e = (blockIdx.x >> 3) * 256 + threadIdx.x;
    if (e >= E) return;
    int c = ei[E + e];
    if (c / partSize != p) return;
    int r = ei[e];
    int pos = atomicAdd(&rowptr[c], 1);
    src_sorted[pos] = r;
    wgt[pos] = dinv[r];
}

// split all three W[128][128] fp32 -> bf16 hi/lo in MFMA B-fragment order:
// idx = ((c*8+t)*64+lane)*8+j <-> W[k][n], k=c*32+(lane>>4)*8+j, n=t*16+(lane&15)
__global__ __launch_bounds__(256) void wsplit_kernel(const float* __restrict__ W1,
                                                     const float* __restrict__ W2,
                                                     const float* __restrict__ W3,
                                                     unsigned short* __restrict__ Wfrag) {
    int layer = blockIdx.x >> 6;
    const float* W = (layer == 0) ? W1 : (layer == 1) ? W2 : W3;
    unsigned short* Whi = Wfrag + layer * 32768;
    unsigned short* Wlo = Whi + 16384;
    int i = (blockIdx.x & 63) * 256 + threadIdx.x;   // 16384 per layer
    int j = i & 7;
    int l = (i >> 3) & 63;
    int t = (i >> 9) & 7;
    int c = i >> 12;
    int k = c * 32 + (l >> 4) * 8 + j;
    int n = t * 16 + (l & 15);
    float v = W[k * 128 + n];
    unsigned short hi = f32_to_bf16_rne(v);
    Whi[i] = hi;
    Wlo[i] = f32_to_bf16_rne(v - bf16_to_f32(hi));
}

// T16 = fp16( act(H_f32) @ W ) via bf16-split MFMA; B-frags from L2-resident global.
__global__ __launch_bounds__(256) void gemm_mfma_kernel(const float* __restrict__ H,
                                                        const unsigned short* __restrict__ Whi,
                                                        const unsigned short* __restrict__ Wlo,
                                                        _Float16* __restrict__ T16,
                                                        int N, int applyRelu) {
    const int tid = threadIdx.x;
    const int wv = tid >> 6;
    const int lane = tid & 63;
    const int r0 = blockIdx.x * 64 + wv * 16;
    const int mrow = lane & 15;
    const int kq = lane >> 4;
    const int grow = r0 + mrow;
    const bool rok = grow < N;

    f32x4 acc[8];
    #pragma unroll
    for (int t = 0; t < 8; ++t) acc[t] = (f32x4){0.f, 0.f, 0.f, 0.f};

    #pragma unroll
    for (int c = 0; c < 4; ++c) {
        float av[8];
        if (rok) {
            const float4* Hp = (const float4*)(H + (size_t)grow * 128 + c * 32 + kq * 8);
            float4 a0 = Hp[0], a1 = Hp[1];
            av[0] = a0.x; av[1] = a0.y; av[2] = a0.z; av[3] = a0.w;
            av[4] = a1.x; av[5] = a1.y; av[6] = a1.z; av[7] = a1.w;
        } else {
            #pragma unroll
            for (int j = 0; j < 8; ++j) av[j] = 0.f;
        }
        bf16x8 ahi, alo;
        #pragma unroll
        for (int j = 0; j < 8; ++j) {
            float v = av[j];
            if (applyRelu) v = fmaxf(v, 0.f);
            unsigned short h = f32_to_bf16_rne(v);
            unsigned short l = f32_to_bf16_rne(v - bf16_to_f32(h));
            ahi[j] = (short)h;
            alo[j] = (short)l;
        }
        #pragma unroll
        for (int t = 0; t < 8; ++t) {
            const int fidx = (((c * 8 + t) * 64) + lane) * 8;
            bf16x8 wh = *(const bf16x8*)&Whi[fidx];
            bf16x8 wl = *(const bf16x8*)&Wlo[fidx];
            acc[t] = __builtin_amdgcn_mfma_f32_16x16x32_bf16(ahi, wh, acc[t], 0, 0, 0);
            acc[t] = __builtin_amdgcn_mfma_f32_16x16x32_bf16(ahi, wl, acc[t], 0, 0, 0);
            acc[t] = __builtin_amdgcn_mfma_f32_16x16x32_bf16(alo, wh, acc[t], 0, 0, 0);
        }
    }
    #pragma unroll
    for (int r = 0; r < 4; ++r) {
        int orow = r0 + kq * 4 + r;
        if (orow < N) {
            _Float16* Tp = T16 + (size_t)orow * 128 + mrow;
            #pragma unroll
            for (int t = 0; t < 8; ++t) Tp[t * 16] = (_Float16)acc[t][r];
        }
    }
}

// one wave per node; 8 lanes/edge x 32B (2 x half8), 8 edges in flight.
// B[n,:] = dinv[n]^2*A[n,:] + bias + sum_e dn*wgt[e]*A[src[e],:]  (fp32 out)
__global__ __launch_bounds__(256) void agg_kernel(const int* __restrict__ rowptr,
                                                  const int* __restrict__ src,
                                                  const float* __restrict__ wgt,
                                                  const float* __restrict__ dinv,
                                                  const _Float16* __restrict__ A16,
                                                  const float* __restrict__ bias,
                                                  float* __restrict__ B, int N) {
    int w = (blockIdx.x * 256 + threadIdx.x) >> 6;
    if (w >= N) return;
    const int lane = threadIdx.x & 63;
    const int g = lane >> 3;           // edge subgroup 0..7
    const int q = lane & 7;            // 32B slot (2 x half8)
    const int beg = (w > 0) ? rowptr[w - 1] : 0;
    const int end = rowptr[w];
    const float dn = dinv[w];
    const half8* A8 = (const half8*)A16;

    float4 a0 = make_float4(0.f, 0.f, 0.f, 0.f);
    float4 a1 = make_float4(0.f, 0.f, 0.f, 0.f);
    float4 a2 = make_float4(0.f, 0.f, 0.f, 0.f);
    float4 a3 = make_float4(0.f, 0.f, 0.f, 0.f);
    for (int e = beg + g; e < end; e += 8) {
        int s = src[e];
        float nrm = dn * wgt[e];
        half8 v0 = A8[(size_t)s * 16 + q * 2];
        half8 v1 = A8[(size_t)s * 16 + q * 2 + 1];
        a0.x = fmaf(nrm, (float)v0[0], a0.x); a0.y = fmaf(nrm, (float)v0[1], a0.y);
        a0.z = fmaf(nrm, (float)v0[2], a0.z); a0.w = fmaf(nrm, (float)v0[3], a0.w);
        a1.x = fmaf(nrm, (float)v0[4], a1.x); a1.y = fmaf(nrm, (float)v0[5], a1.y);
        a1.z = fmaf(nrm, (float)v0[6], a1.z); a1.w = fmaf(nrm, (float)v0[7], a1.w);
        a2.x = fmaf(nrm, (float)v1[0], a2.x); a2.y = fmaf(nrm, (float)v1[1], a2.y);
        a2.z = fmaf(nrm, (float)v1[2], a2.z); a2.w = fmaf(nrm, (float)v1[3], a2.w);
        a3.x = fmaf(nrm, (float)v1[4], a3.x); a3.y = fmaf(nrm, (float)v1[5], a3.y);
        a3.z = fmaf(nrm, (float)v1[6], a3.z); a3.w = fmaf(nrm, (float)v1[7], a3.w);
    }
    // merge 8 groups (lanes differing in bits 3,4,5)
    #pragma unroll
    for (int m = 8; m <= 32; m <<= 1) {
        a0.x += __shfl_xor(a0.x, m); a0.y += __shfl_xor(a0.y, m);
        a0.z += __shfl_xor(a0.z, m); a0.w += __shfl_xor(a0.w, m);
        a1.x += __shfl_xor(a1.x, m); a1.y += __shfl_xor(a1.y, m);
        a1.z += __shfl_xor(a1.z, m); a1.w += __shfl_xor(a1.w, m);
        a2.x += __shfl_xor(a2.x, m); a2.y += __shfl_xor(a2.y, m);
        a2.z += __shfl_xor(a2.z, m); a2.w += __shfl_xor(a2.w, m);
        a3.x += __shfl_xor(a3.x, m); a3.y += __shfl_xor(a3.y, m);
        a3.z += __shfl_xor(a3.z, m); a3.w += __shfl_xor(a3.w, m);
    }

    if (g == 0) {
        half8 s0 = A8[(size_t)w * 16 + q * 2];
        half8 s1 = A8[(size_t)w * 16 + q * 2 + 1];
        float4 b0 = ((const float4*)bias)[q * 4];
        float4 b1 = ((const float4*)bias)[q * 4 + 1];
        float4 b2 = ((const float4*)bias)[q * 4 + 2];
        float4 b3 = ((const float4*)bias)[q * 4 + 3];
        float d2 = dn * dn;
        a0.x = fmaf(d2, (float)s0[0], a0.x + b0.x);
        a0.y = fmaf(d2, (float)s0[1], a0.y + b0.y);
        a0.z = fmaf(d2, (float)s0[2], a0.z + b0.z);
        a0.w = fmaf(d2, (float)s0[3], a0.w + b0.w);
        a1.x = fmaf(d2, (float)s0[4], a1.x + b1.x);
        a1.y = fmaf(d2, (float)s0[5], a1.y + b1.y);
        a1.z = fmaf(d2, (float)s0[6], a1.z + b1.z);
        a1.w = fmaf(d2, (float)s0[7], a1.w + b1.w);
        a2.x = fmaf(d2, (float)s1[0], a2.x + b2.x);
        a2.y = fmaf(d2, (float)s1[1], a2.y + b2.y);
        a2.z = fmaf(d2, (float)s1[2], a2.z + b2.z);
        a2.w = fmaf(d2, (float)s1[3], a2.w + b2.w);
        a3.x = fmaf(d2, (float)s1[4], a3.x + b3.x);
        a3.y = fmaf(d2, (float)s1[5], a3.y + b3.y);
        a3.z = fmaf(d2, (float)s1[6], a3.z + b3.z);
        a3.w = fmaf(d2, (float)s1[7], a3.w + b3.w);
        float4* Bp = (float4*)B + (size_t)w * 32 + q * 4;
        Bp[0] = a0; Bp[1] = a1; Bp[2] = a2; Bp[3] = a3;
    }
}

// layer-3 head: agg (8 edges in flight) then nodeval[n] = dot(relu(row), lin_w)
__global__ __launch_bounds__(256) void agg_head_kernel(const int* __restrict__ rowptr,
                                                       const int* __restrict__ src,
                                                       const float* __restrict__ wgt,
                                                       const float* __restrict__ dinv,
                                                       const _Float16* __restrict__ A16,
                                                       const float* __restrict__ bias,
                                                       const float* __restrict__ lin_w,
                                                       float* __restrict__ nodeval, int N) {
    int w = (blockIdx.x * 256 + threadIdx.x) >> 6;
    if (w >= N) return;
    const int lane = threadIdx.x & 63;
    const int g = lane >> 3;
    const int q = lane & 7;
    const int beg = (w > 0) ? rowptr[w - 1] : 0;
    const int end = rowptr[w];
    const float dn = dinv[w];
    const half8* A8 = (const half8*)A16;

    float4 a0 = make_float4(0.f, 0.f, 0.f, 0.f);
    float4 a1 = make_float4(0.f, 0.f, 0.f, 0.f);
    float4 a2 = make_float4(0.f, 0.f, 0.f, 0.f);
    float4 a3 = make_float4(0.f, 0.f, 0.f, 0.f);
    for (int e = beg + g; e < end; e += 8) {
        int s = src[e];
        float nrm = dn * wgt[e];
        half8 v0 = A8[(size_t)s * 16 + q * 2];
        half8 v1 = A8[(size_t)s * 16 + q * 2 + 1];
        a0.x = fmaf(nrm, (float)v0[0], a0.x); a0.y = fmaf(nrm, (float)v0[1], a0.y);
        a0.z = fmaf(nrm, (float)v0[2], a0.z); a0.w = fmaf(nrm, (float)v0[3], a0.w);
        a1.x = fmaf(nrm, (float)v0[4], a1.x); a1.y = fmaf(nrm, (float)v0[5], a1.y);
        a1.z = fmaf(nrm, (float)v0[6], a1.z); a1.w = fmaf(nrm, (float)v0[7], a1.w);
        a2.x = fmaf(nrm, (float)v1[0], a2.x); a2.y = fmaf(nrm, (float)v1[1], a2.y);
        a2.z = fmaf(nrm, (float)v1[2], a2.z); a2.w = fmaf(nrm, (float)v1[3], a2.w);
        a3.x = fmaf(nrm, (float)v1[4], a3.x); a3.y = fmaf(nrm, (float)v1[5], a3.y);
        a3.z = fmaf(nrm, (float)v1[6], a3.z); a3.w = fmaf(nrm, (float)v1[7], a3.w);
    }
    #pragma unroll
    for (int m = 8; m <= 32; m <<= 1) {
        a0.x += __shfl_xor(a0.x, m); a0.y += __shfl_xor(a0.y, m);
        a0.z += __shfl_xor(a0.z, m); a0.w += __shfl_xor(a0.w, m);
        a1.x += __shfl_xor(a1.x, m); a1.y += __shfl_xor(a1.y, m);
        a1.z += __shfl_xor(a1.z, m); a1.w += __shfl_xor(a1.w, m);
        a2.x += __shfl_xor(a2.x, m); a2.y += __shfl_xor(a2.y, m);
        a2.z += __shfl_xor(a2.z, m); a2.w += __shfl_xor(a2.w, m);
        a3.x += __shfl_xor(a3.x, m); a3.y += __shfl_xor(a3.y, m);
        a3.z += __shfl_xor(a3.z, m); a3.w += __shfl_xor(a3.w, m);
    }

    if (g == 0) {
        half8 s0 = A8[(size_t)w * 16 + q * 2];
        half8 s1 = A8[(size_t)w * 16 + q * 2 + 1];
        float4 b0 = ((const float4*)bias)[q * 4];
        float4 b1 = ((const float4*)bias)[q * 4 + 1];
        float4 b2 = ((const float4*)bias)[q * 4 + 2];
        float4 b3 = ((const float4*)bias)[q * 4 + 3];
        float d2 = dn * dn;
        a0.x = fmaf(d2, (float)s0[0], a0.x + b0.x);
        a0.y = fmaf(d2, (float)s0[1], a0.y + b0.y);
        a0.z = fmaf(d2, (float)s0[2], a0.z + b0.z);
        a0.w = fmaf(d2, (float)s0[3], a0.w + b0.w);
        a1.x = fmaf(d2, (float)s0[4], a1.x + b1.x);
        a1.y = fmaf(d2, (float)s0[5], a1.y + b1.y);
        a1.z = fmaf(d2, (float)s0[6], a1.z + b1.z);
        a1.w = fmaf(d2, (float)s0[7], a1.w + b1.w);
        a2.x = fmaf(d2, (float)s1[0], a2.x + b2.x);
        a2.y = fmaf(d2, (float)s1[1], a2.y + b2.y);
        a2.z = fmaf(d2, (float)s1[2], a2.z + b2.z);
        a2.w = fmaf(d2, (float)s1[3], a2.w + b2.w);
        a3.x = fmaf(d2, (float)s1[4], a3.x + b3.x);
        a3.y = fmaf(d2, (float)s1[5], a3.y + b3.y);
        a3.z = fmaf(d2, (float)s1[6], a3.z + b3.z);
        a3.w = fmaf(d2, (float)s1[7], a3.w + b3.w);
        float4 w0 = ((const float4*)lin_w)[q * 4];
        float4 w1 = ((const float4*)lin_w)[q * 4 + 1];
        float4 w2 = ((const float4*)lin_w)[q * 4 + 2];
        float4 w3 = ((const float4*)lin_w)[q * 4 + 3];
        float s = fmaxf(a0.x, 0.f) * w0.x + fmaxf(a0.y, 0.f) * w0.y
                + fmaxf(a0.z, 0.f) * w0.z + fmaxf(a0.w, 0.f) * w0.w
                + fmaxf(a1.x, 0.f) * w1.x + fmaxf(a1.y, 0.f) * w1.y
                + fmaxf(a1.z, 0.f) * w1.z + fmaxf(a1.w, 0.f) * w1.w
                + fmaxf(a2.x, 0.f) * w2.x + fmaxf(a2.y, 0.f) * w2.y
                + fmaxf(a2.z, 0.f) * w2.z + fmaxf(a2.w, 0.f) * w2.w
                + fmaxf(a3.x, 0.f) * w3.x + fmaxf(a3.y, 0.f) * w3.y
                + fmaxf(a3.z, 0.f) * w3.z + fmaxf(a3.w, 0.f) * w3.w;
        s += __shfl_xor(s, 1);
        s += __shfl_xor(s, 2);
        s += __shfl_xor(s, 4);
        if (q == 0) nodeval[w] = s;
    }
}

__device__ __forceinline__ int lower_bound_dev(const int* __restrict__ a, int n, int key) {
    int lo = 0, hi = n;
    while (lo < hi) {
        int mid = (lo + hi) >> 1;
        if (a[mid] < key) lo = mid + 1; else hi = mid;
    }
    return lo;
}

// one block per graph: out[g] = mean(nodeval[lo:hi]) + lin_b  (batch is sorted)
__global__ __launch_bounds__(256) void segreduce_kernel(const float* __restrict__ nodeval,
                                                        const int* __restrict__ batch,
                                                        const float* __restrict__ lin_b,
                                                        float* __restrict__ out, int N) {
    const int g = blockIdx.x;
    const int lo = lower_bound_dev(batch, N, g);
    const int hi = lower_bound_dev(batch, N, g + 1);
    float acc = 0.f;
    for (int n = lo + threadIdx.x; n < hi; n += 256) acc += nodeval[n];
    __shared__ float red[256];
    red[threadIdx.x] = acc;
    __syncthreads();
    for (int s = 128; s > 0; s >>= 1) {
        if (threadIdx.x < s) red[threadIdx.x] += red[threadIdx.x + s];
        __syncthreads();
    }
    if (threadIdx.x == 0) {
        float cnt = (float)(hi - lo);
        out[g] = red[0] / fmaxf(cnt, 1.0f) + lin_b[0];
    }
}

extern "C" void kernel_launch(void* const* d_in, const int* in_sizes, int n_in,
                              void* d_out, int out_size, void* d_ws, size_t ws_size,
                              hipStream_t stream) {
    const float* x     = (const float*)d_in[0];
    const int*   ei    = (const int*)d_in[1];    // [2,E]: rows then cols
    const int*   batch = (const int*)d_in[2];
    const float* W1    = (const float*)d_in[3];
    const float* b1    = (const float*)d_in[4];
    const float* W2    = (const float*)d_in[5];
    const float* b2    = (const float*)d_in[6];
    const float* W3    = (const float*)d_in[7];
    const float* b3    = (const float*)d_in[8];
    const float* lin_w = (const float*)d_in[9];
    const float* lin_b = (const float*)d_in[10];
    float* out = (float*)d_out;

    const int N = in_sizes[0] / 128;
    const int E = in_sizes[1] / 2;
    const int nBlk = (N + 1023) / 1024;
    const int partSize = (N + 7) / 8;            // XCD destination partition
    const int eChunks = (E + 255) / 256;

    // workspace: A16 | B | deg | dinv | rowptr | src | wgt | scan | nodeval | Wfrag
    _Float16* A16    = (_Float16*)d_ws;
    float* B         = (float*)(A16 + (size_t)N * 128);
    int*   deg       = (int*)(B + (size_t)N * 128);
    float* dinv      = (float*)(deg + N);
    int*   rowptr    = (int*)(dinv + N);
    int*   src_srt   = rowptr + N;
    float* wgt       = (float*)(src_srt + E);
    int*   blockSums = (int*)(wgt + E);
    int*   blockOffs = blockSums + 256;
    float* nodeval   = (float*)(blockOffs + 256);
    unsigned short* Wfrag = (unsigned short*)(nodeval + N);  // 3 x (hi|lo) x 16384

    // ---- CSR build ----
    hipMemsetAsync(deg, 0, (size_t)N * sizeof(int), stream);
    count_deg_kernel<<<8 * eChunks, 256, 0, stream>>>(ei + E, deg, E, partSize);
    scan1_kernel<<<nBlk, 256, 0, stream>>>(deg, rowptr, dinv, blockSums, N);
    scan2_kernel<<<1, 128, 0, stream>>>(blockSums, blockOffs, nBlk);
    scan3_kernel<<<(N + 255) / 256, 256, 0, stream>>>(rowptr, blockOffs, N);
    fill_kernel<<<8 * eChunks, 256, 0, stream>>>(ei, dinv, rowptr, src_srt, wgt,
                                                 E, partSize);
    wsplit_kernel<<<192, 256, 0, stream>>>(W1, W2, W3, Wfrag);

    const int gBlocks = (N + 63) / 64;
    const int aBlocks = ((size_t)N * 64 + 255) / 256;

    // layer 1: x @ W1 -> A16 ; agg -> B
    gemm_mfma_kernel<<<gBlocks, 256, 0, stream>>>(x, Wfrag, Wfrag + 16384, A16, N, 0);
    agg_kernel<<<aBlocks, 256, 0, stream>>>(rowptr, src_srt, wgt, dinv, A16, b1, B, N);
    // layer 2: relu(B) @ W2 -> A16 ; agg -> B
    gemm_mfma_kernel<<<gBlocks, 256, 0, stream>>>(B, Wfrag + 32768,
                                                  Wfrag + 32768 + 16384, A16, N, 1);
    agg_kernel<<<aBlocks, 256, 0, stream>>>(rowptr, src_srt, wgt, dinv, A16, b2, B, N);
    // layer 3: relu(B) @ W3 -> A16 ; head agg + dot -> nodeval
    gemm_mfma_kernel<<<gBlocks, 256, 0, stream>>>(B, Wfrag + 65536,
                                                  Wfrag + 65536 + 16384, A16, N, 1);
    agg_head_kernel<<<aBlocks, 256, 0, stream>>>(rowptr, src_srt, wgt, dinv,
                                                 A16, b3, lin_w, nodeval, N);
    segreduce_kernel<<<64, 256, 0, stream>>>(nodeval, batch, lin_b, out, N);
}

// Round 11
// 530.852 us; speedup vs baseline: 1.2012x; 1.0420x over previous
//
#include <hip/hip_runtime.h>

// ---------------------------------------------------------------------------
// GCN forward (R10 + int2 edge records + fp16 post-relu hidden state):
//   build: XCD-partitioned deg count -> scan(+dinv) -> XCD-partitioned fill
//          (edges[pos] = {src, dinv[src]} single 8B scatter)
//   W prep: one kernel splits all 3 fp32 W -> bf16 hi/lo in MFMA B-frag order
//   layer1: x(f32) @ W1 -> A16 ; agg -> H16 (relu'd fp16)
//   layer2: H16 @ W2 -> A16 ; agg -> H16
//   layer3: H16 @ W3 -> A16 ; head agg + lin_w dot -> nodeval -> segreduce
// ---------------------------------------------------------------------------

typedef __attribute__((ext_vector_type(8))) short bf16x8;
typedef __attribute__((ext_vector_type(4))) float f32x4;
typedef __attribute__((ext_vector_type(8))) _Float16 half8;

__device__ __forceinline__ unsigned short f32_to_bf16_rne(float f) {
    unsigned u = __float_as_uint(f);
    unsigned r = u + 0x7FFF + ((u >> 16) & 1);
    return (unsigned short)(r >> 16);
}
__device__ __forceinline__ float bf16_to_f32(unsigned short h) {
    return __uint_as_float(((unsigned)h) << 16);
}

// XCD-partitioned degree count (8 blocks round-robin -> 8 XCDs share each chunk)
__global__ __launch_bounds__(256) void count_deg_kernel(const int* __restrict__ col,
                                                        int* __restrict__ deg,
                                                        int E, int partSize) {
    const int p = blockIdx.x & 7;
    const int e = (blockIdx.x >> 3) * 256 + threadIdx.x;
    if (e >= E) return;
    int c = col[e];
    if (c / partSize == p) atomicAdd(&deg[c], 1);
}

// per-block exclusive scan of deg (1024/block) -> rowptr; also dinv = rsqrt(deg+1)
__global__ __launch_bounds__(256) void scan1_kernel(const int* __restrict__ deg,
                                                    int* __restrict__ rowptr,
                                                    float* __restrict__ dinv,
                                                    int* __restrict__ blockSums, int N) {
    __shared__ int ts[256];
    const int t = threadIdx.x;
    const int base = blockIdx.x * 1024 + t * 4;
    int v0 = 0, v1 = 0, v2 = 0, v3 = 0;
    if (base + 3 < N) {
        int4 v = *(const int4*)&deg[base];
        v0 = v.x; v1 = v.y; v2 = v.z; v3 = v.w;
    } else {
        if (base + 0 < N) v0 = deg[base + 0];
        if (base + 1 < N) v1 = deg[base + 1];
        if (base + 2 < N) v2 = deg[base + 2];
        if (base + 3 < N) v3 = deg[base + 3];
    }
    if (base + 0 < N) dinv[base + 0] = 1.0f / sqrtf((float)v0 + 1.0f);
    if (base + 1 < N) dinv[base + 1] = 1.0f / sqrtf((float)v1 + 1.0f);
    if (base + 2 < N) dinv[base + 2] = 1.0f / sqrtf((float)v2 + 1.0f);
    if (base + 3 < N) dinv[base + 3] = 1.0f / sqrtf((float)v3 + 1.0f);
    const int tot = v0 + v1 + v2 + v3;
    ts[t] = tot;
    __syncthreads();
    for (int off = 1; off < 256; off <<= 1) {
        int add = (t >= off) ? ts[t - off] : 0;
        __syncthreads();
        ts[t] += add;
        __syncthreads();
    }
    const int excl = ts[t] - tot;
    if (base + 0 < N) rowptr[base + 0] = excl;
    if (base + 1 < N) rowptr[base + 1] = excl + v0;
    if (base + 2 < N) rowptr[base + 2] = excl + v0 + v1;
    if (base + 3 < N) rowptr[base + 3] = excl + v0 + v1 + v2;
    if (t == 255) blockSums[blockIdx.x] = ts[255];
}

__global__ __launch_bounds__(128) void scan2_kernel(const int* __restrict__ blockSums,
                                                    int* __restrict__ blockOffs, int B) {
    __shared__ int ts[128];
    const int t = threadIdx.x;
    ts[t] = (t < B) ? blockSums[t] : 0;
    __syncthreads();
    for (int off = 1; off < 128; off <<= 1) {
        int add = (t >= off) ? ts[t - off] : 0;
        __syncthreads();
        ts[t] += add;
        __syncthreads();
    }
    if (t < B) blockOffs[t] = ts[t];
}

__global__ __launch_bounds__(256) void scan3_kernel(int* __restrict__ rowptr,
                                                    const int* __restrict__ blockOffs, int N) {
    int i = blockIdx.x * 256 + threadIdx.x;
    if (i >= N) return;
    int b = i >> 10;
    if (b > 0) rowptr[i] += blockOffs[b - 1];
}

// XCD-partitioned counting-sort fill: one int2 {src, dinv[src]} scatter per edge
__global__ __launch_bounds__(256) void fill_kernel(const int* __restrict__ ei,
                                                   const float* __restrict__ dinv,
                                                   int* __restrict__ rowptr,
                                                   int2* __restrict__ edges,
                                                   int E, int partSize) {
    const int p = blockIdx.x & 7;
    const int e = (blockIdx.x >> 3) * 256 + threadIdx.x;
    if (e >= E) return;
    int c = ei[E + e];
    if (c / partSize != p) return;
    int r = ei[e];
    int pos = atomicAdd(&rowptr[c], 1);
    edges[pos] = make_int2(r, __float_as_int(dinv[r]));
}

// split all three W[128][128] fp32 -> bf16 hi/lo in MFMA B-fragment order:
// idx = ((c*8+t)*64+lane)*8+j <-> W[k][n], k=c*32+(lane>>4)*8+j, n=t*16+(lane&15)
__global__ __launch_bounds__(256) void wsplit_kernel(const float* __restrict__ W1,
                                                     const float* __restrict__ W2,
                                                     const float* __restrict__ W3,
                                                     unsigned short* __restrict__ Wfrag) {
    int layer = blockIdx.x >> 6;
    const float* W = (layer == 0) ? W1 : (layer == 1) ? W2 : W3;
    unsigned short* Whi = Wfrag + layer * 32768;
    unsigned short* Wlo = Whi + 16384;
    int i = (blockIdx.x & 63) * 256 + threadIdx.x;   // 16384 per layer
    int j = i & 7;
    int l = (i >> 3) & 63;
    int t = (i >> 9) & 7;
    int c = i >> 12;
    int k = c * 32 + (l >> 4) * 8 + j;
    int n = t * 16 + (l & 15);
    float v = W[k * 128 + n];
    unsigned short hi = f32_to_bf16_rne(v);
    Whi[i] = hi;
    Wlo[i] = f32_to_bf16_rne(v - bf16_to_f32(hi));
}

// A16 = fp16( H_f32 @ W ) via bf16-split MFMA (layer 1; x input, no relu)
__global__ __launch_bounds__(256) void gemm_f32_kernel(const float* __restrict__ H,
                                                       const unsigned short* __restrict__ Whi,
                                                       const unsigned short* __restrict__ Wlo,
                                                       _Float16* __restrict__ T16,
                                                       int N) {
    const int tid = threadIdx.x;
    const int wv = tid >> 6;
    const int lane = tid & 63;
    const int r0 = blockIdx.x * 64 + wv * 16;
    const int mrow = lane & 15;
    const int kq = lane >> 4;
    const int grow = r0 + mrow;
    const bool rok = grow < N;

    f32x4 acc[8];
    #pragma unroll
    for (int t = 0; t < 8; ++t) acc[t] = (f32x4){0.f, 0.f, 0.f, 0.f};

    #pragma unroll
    for (int c = 0; c < 4; ++c) {
        float av[8];
        if (rok) {
            const float4* Hp = (const float4*)(H + (size_t)grow * 128 + c * 32 + kq * 8);
            float4 a0 = Hp[0], a1 = Hp[1];
            av[0] = a0.x; av[1] = a0.y; av[2] = a0.z; av[3] = a0.w;
            av[4] = a1.x; av[5] = a1.y; av[6] = a1.z; av[7] = a1.w;
        } else {
            #pragma unroll
            for (int j = 0; j < 8; ++j) av[j] = 0.f;
        }
        bf16x8 ahi, alo;
        #pragma unroll
        for (int j = 0; j < 8; ++j) {
            float v = av[j];
            unsigned short h = f32_to_bf16_rne(v);
            unsigned short l = f32_to_bf16_rne(v - bf16_to_f32(h));
            ahi[j] = (short)h;
            alo[j] = (short)l;
        }
        #pragma unroll
        for (int t = 0; t < 8; ++t) {
            const int fidx = (((c * 8 + t) * 64) + lane) * 8;
            bf16x8 wh = *(const bf16x8*)&Whi[fidx];
            bf16x8 wl = *(const bf16x8*)&Wlo[fidx];
            acc[t] = __builtin_amdgcn_mfma_f32_16x16x32_bf16(ahi, wh, acc[t], 0, 0, 0);
            acc[t] = __builtin_amdgcn_mfma_f32_16x16x32_bf16(ahi, wl, acc[t], 0, 0, 0);
            acc[t] = __builtin_amdgcn_mfma_f32_16x16x32_bf16(alo, wh, acc[t], 0, 0, 0);
        }
    }
    #pragma unroll
    for (int r = 0; r < 4; ++r) {
        int orow = r0 + kq * 4 + r;
        if (orow < N) {
            _Float16* Tp = T16 + (size_t)orow * 128 + mrow;
            #pragma unroll
            for (int t = 0; t < 8; ++t) Tp[t * 16] = (_Float16)acc[t][r];
        }
    }
}

// A16 = fp16( H16 @ W ) via bf16-split MFMA (layers 2/3; fp16 relu'd input).
// hi+lo bf16 split of an fp16 value is exact.
__global__ __launch_bounds__(256) void gemm_f16_kernel(const _Float16* __restrict__ H16,
                                                       const unsigned short* __restrict__ Whi,
                                                       const unsigned short* __restrict__ Wlo,
                                                       _Float16* __restrict__ T16,
                                                       int N) {
    const int tid = threadIdx.x;
    const int wv = tid >> 6;
    const int lane = tid & 63;
    const int r0 = blockIdx.x * 64 + wv * 16;
    const int mrow = lane & 15;
    const int kq = lane >> 4;
    const int grow = r0 + mrow;
    const bool rok = grow < N;

    f32x4 acc[8];
    #pragma unroll
    for (int t = 0; t < 8; ++t) acc[t] = (f32x4){0.f, 0.f, 0.f, 0.f};

    #pragma unroll
    for (int c = 0; c < 4; ++c) {
        half8 hv = (half8)(_Float16)0;
        if (rok) hv = *(const half8*)(H16 + (size_t)grow * 128 + c * 32 + kq * 8);
        bf16x8 ahi, alo;
        #pragma unroll
        for (int j = 0; j < 8; ++j) {
            float v = (float)hv[j];
            unsigned short h = f32_to_bf16_rne(v);
            unsigned short l = f32_to_bf16_rne(v - bf16_to_f32(h));
            ahi[j] = (short)h;
            alo[j] = (short)l;
        }
        #pragma unroll
        for (int t = 0; t < 8; ++t) {
            const int fidx = (((c * 8 + t) * 64) + lane) * 8;
            bf16x8 wh = *(const bf16x8*)&Whi[fidx];
            bf16x8 wl = *(const bf16x8*)&Wlo[fidx];
            acc[t] = __builtin_amdgcn_mfma_f32_16x16x32_bf16(ahi, wh, acc[t], 0, 0, 0);
            acc[t] = __builtin_amdgcn_mfma_f32_16x16x32_bf16(ahi, wl, acc[t], 0, 0, 0);
            acc[t] = __builtin_amdgcn_mfma_f32_16x16x32_bf16(alo, wh, acc[t], 0, 0, 0);
        }
    }
    #pragma unroll
    for (int r = 0; r < 4; ++r) {
        int orow = r0 + kq * 4 + r;
        if (orow < N) {
            _Float16* Tp = T16 + (size_t)orow * 128 + mrow;
            #pragma unroll
            for (int t = 0; t < 8; ++t) Tp[t * 16] = (_Float16)acc[t][r];
        }
    }
}

// one wave per node; 8 lanes/edge x 32B (2 x half8), 8 edges in flight.
// H16[n,:] = fp16(relu( dinv[n]^2*A[n,:] + bias + sum_e dn*w_e*A[src_e,:] ))
__global__ __launch_bounds__(256) void agg_kernel(const int* __restrict__ rowptr,
                                                  const int2* __restrict__ edges,
                                                  const float* __restrict__ dinv,
                                                  const _Float16* __restrict__ A16,
                                                  const float* __restrict__ bias,
                                                  _Float16* __restrict__ H16, int N) {
    int w = (blockIdx.x * 256 + threadIdx.x) >> 6;
    if (w >= N) return;
    const int lane = threadIdx.x & 63;
    const int g = lane >> 3;           // edge subgroup 0..7
    const int q = lane & 7;            // 32B slot (2 x half8)
    const int beg = (w > 0) ? rowptr[w - 1] : 0;
    const int end = rowptr[w];
    const float dn = dinv[w];
    const half8* A8 = (const half8*)A16;

    float4 a0 = make_float4(0.f, 0.f, 0.f, 0.f);
    float4 a1 = make_float4(0.f, 0.f, 0.f, 0.f);
    float4 a2 = make_float4(0.f, 0.f, 0.f, 0.f);
    float4 a3 = make_float4(0.f, 0.f, 0.f, 0.f);
    for (int e = beg + g; e < end; e += 8) {
        int2 ed = edges[e];
        int s = ed.x;
        float nrm = dn * __int_as_float(ed.y);
        half8 v0 = A8[(size_t)s * 16 + q * 2];
        half8 v1 = A8[(size_t)s * 16 + q * 2 + 1];
        a0.x = fmaf(nrm, (float)v0[0], a0.x); a0.y = fmaf(nrm, (float)v0[1], a0.y);
        a0.z = fmaf(nrm, (float)v0[2], a0.z); a0.w = fmaf(nrm, (float)v0[3], a0.w);
        a1.x = fmaf(nrm, (float)v0[4], a1.x); a1.y = fmaf(nrm, (float)v0[5], a1.y);
        a1.z = fmaf(nrm, (float)v0[6], a1.z); a1.w = fmaf(nrm, (float)v0[7], a1.w);
        a2.x = fmaf(nrm, (float)v1[0], a2.x); a2.y = fmaf(nrm, (float)v1[1], a2.y);
        a2.z = fmaf(nrm, (float)v1[2], a2.z); a2.w = fmaf(nrm, (float)v1[3], a2.w);
        a3.x = fmaf(nrm, (float)v1[4], a3.x); a3.y = fmaf(nrm, (float)v1[5], a3.y);
        a3.z = fmaf(nrm, (float)v1[6], a3.z); a3.w = fmaf(nrm, (float)v1[7], a3.w);
    }
    #pragma unroll
    for (int m = 8; m <= 32; m <<= 1) {
        a0.x += __shfl_xor(a0.x, m); a0.y += __shfl_xor(a0.y, m);
        a0.z += __shfl_xor(a0.z, m); a0.w += __shfl_xor(a0.w, m);
        a1.x += __shfl_xor(a1.x, m); a1.y += __shfl_xor(a1.y, m);
        a1.z += __shfl_xor(a1.z, m); a1.w += __shfl_xor(a1.w, m);
        a2.x += __shfl_xor(a2.x, m); a2.y += __shfl_xor(a2.y, m);
        a2.z += __shfl_xor(a2.z, m); a2.w += __shfl_xor(a2.w, m);
        a3.x += __shfl_xor(a3.x, m); a3.y += __shfl_xor(a3.y, m);
        a3.z += __shfl_xor(a3.z, m); a3.w += __shfl_xor(a3.w, m);
    }

    if (g == 0) {
        half8 s0 = A8[(size_t)w * 16 + q * 2];
        half8 s1 = A8[(size_t)w * 16 + q * 2 + 1];
        float4 b0 = ((const float4*)bias)[q * 4];
        float4 b1 = ((const float4*)bias)[q * 4 + 1];
        float4 b2 = ((const float4*)bias)[q * 4 + 2];
        float4 b3 = ((const float4*)bias)[q * 4 + 3];
        float d2 = dn * dn;
        half8 o0, o1;
        o0[0] = (_Float16)fmaxf(fmaf(d2, (float)s0[0], a0.x + b0.x), 0.f);
        o0[1] = (_Float16)fmaxf(fmaf(d2, (float)s0[1], a0.y + b0.y), 0.f);
        o0[2] = (_Float16)fmaxf(fmaf(d2, (float)s0[2], a0.z + b0.z), 0.f);
        o0[3] = (_Float16)fmaxf(fmaf(d2, (float)s0[3], a0.w + b0.w), 0.f);
        o0[4] = (_Float16)fmaxf(fmaf(d2, (float)s0[4], a1.x + b1.x), 0.f);
        o0[5] = (_Float16)fmaxf(fmaf(d2, (float)s0[5], a1.y + b1.y), 0.f);
        o0[6] = (_Float16)fmaxf(fmaf(d2, (float)s0[6], a1.z + b1.z), 0.f);
        o0[7] = (_Float16)fmaxf(fmaf(d2, (float)s0[7], a1.w + b1.w), 0.f);
        o1[0] = (_Float16)fmaxf(fmaf(d2, (float)s1[0], a2.x + b2.x), 0.f);
        o1[1] = (_Float16)fmaxf(fmaf(d2, (float)s1[1], a2.y + b2.y), 0.f);
        o1[2] = (_Float16)fmaxf(fmaf(d2, (float)s1[2], a2.z + b2.z), 0.f);
        o1[3] = (_Float16)fmaxf(fmaf(d2, (float)s1[3], a2.w + b2.w), 0.f);
        o1[4] = (_Float16)fmaxf(fmaf(d2, (float)s1[4], a3.x + b3.x), 0.f);
        o1[5] = (_Float16)fmaxf(fmaf(d2, (float)s1[5], a3.y + b3.y), 0.f);
        o1[6] = (_Float16)fmaxf(fmaf(d2, (float)s1[6], a3.z + b3.z), 0.f);
        o1[7] = (_Float16)fmaxf(fmaf(d2, (float)s1[7], a3.w + b3.w), 0.f);
        half8* Hp = (half8*)H16 + (size_t)w * 16 + q * 2;
        Hp[0] = o0;
        Hp[1] = o1;
    }
}

// layer-3 head: agg (8 edges in flight) then nodeval[n] = dot(relu(row), lin_w)
__global__ __launch_bounds__(256) void agg_head_kernel(const int* __restrict__ rowptr,
                                                       const int2* __restrict__ edges,
                                                       const float* __restrict__ dinv,
                                                       const _Float16* __restrict__ A16,
                                                       const float* __restrict__ bias,
                                                       const float* __restrict__ lin_w,
                                                       float* __restrict__ nodeval, int N) {
    int w = (blockIdx.x * 256 + threadIdx.x) >> 6;
    if (w >= N) return;
    const int lane = threadIdx.x & 63;
    const int g = lane >> 3;
    const int q = lane & 7;
    const int beg = (w > 0) ? rowptr[w - 1] : 0;
    const int end = rowptr[w];
    const float dn = dinv[w];
    const half8* A8 = (const half8*)A16;

    float4 a0 = make_float4(0.f, 0.f, 0.f, 0.f);
    float4 a1 = make_float4(0.f, 0.f, 0.f, 0.f);
    float4 a2 = make_float4(0.f, 0.f, 0.f, 0.f);
    float4 a3 = make_float4(0.f, 0.f, 0.f, 0.f);
    for (int e = beg + g; e < end; e += 8) {
        int2 ed = edges[e];
        int s = ed.x;
        float nrm = dn * __int_as_float(ed.y);
        half8 v0 = A8[(size_t)s * 16 + q * 2];
        half8 v1 = A8[(size_t)s * 16 + q * 2 + 1];
        a0.x = fmaf(nrm, (float)v0[0], a0.x); a0.y = fmaf(nrm, (float)v0[1], a0.y);
        a0.z = fmaf(nrm, (float)v0[2], a0.z); a0.w = fmaf(nrm, (float)v0[3], a0.w);
        a1.x = fmaf(nrm, (float)v0[4], a1.x); a1.y = fmaf(nrm, (float)v0[5], a1.y);
        a1.z = fmaf(nrm, (float)v0[6], a1.z); a1.w = fmaf(nrm, (float)v0[7], a1.w);
        a2.x = fmaf(nrm, (float)v1[0], a2.x); a2.y = fmaf(nrm, (float)v1[1], a2.y);
        a2.z = fmaf(nrm, (float)v1[2], a2.z); a2.w = fmaf(nrm, (float)v1[3], a2.w);
        a3.x = fmaf(nrm, (float)v1[4], a3.x); a3.y = fmaf(nrm, (float)v1[5], a3.y);
        a3.z = fmaf(nrm, (float)v1[6], a3.z); a3.w = fmaf(nrm, (float)v1[7], a3.w);
    }
    #pragma unroll
    for (int m = 8; m <= 32; m <<= 1) {
        a0.x += __shfl_xor(a0.x, m); a0.y += __shfl_xor(a0.y, m);
        a0.z += __shfl_xor(a0.z, m); a0.w += __shfl_xor(a0.w, m);
        a1.x += __shfl_xor(a1.x, m); a1.y += __shfl_xor(a1.y, m);
        a1.z += __shfl_xor(a1.z, m); a1.w += __shfl_xor(a1.w, m);
        a2.x += __shfl_xor(a2.x, m); a2.y += __shfl_xor(a2.y, m);
        a2.z += __shfl_xor(a2.z, m); a2.w += __shfl_xor(a2.w, m);
        a3.x += __shfl_xor(a3.x, m); a3.y += __shfl_xor(a3.y, m);
        a3.z += __shfl_xor(a3.z, m); a3.w += __shfl_xor(a3.w, m);
    }

    if (g == 0) {
        half8 s0 = A8[(size_t)w * 16 + q * 2];
        half8 s1 = A8[(size_t)w * 16 + q * 2 + 1];
        float4 b0 = ((const float4*)bias)[q * 4];
        float4 b1 = ((const float4*)bias)[q * 4 + 1];
        float4 b2 = ((const float4*)bias)[q * 4 + 2];
        float4 b3 = ((const float4*)bias)[q * 4 + 3];
        float d2 = dn * dn;
        a0.x = fmaf(d2, (float)s0[0], a0.x + b0.x);
        a0.y = fmaf(d2, (float)s0[1], a0.y + b0.y);
        a0.z = fmaf(d2, (float)s0[2], a0.z + b0.z);
        a0.w = fmaf(d2, (float)s0[3], a0.w + b0.w);
        a1.x = fmaf(d2, (float)s0[4], a1.x + b1.x);
        a1.y = fmaf(d2, (float)s0[5], a1.y + b1.y);
        a1.z = fmaf(d2, (float)s0[6], a1.z + b1.z);
        a1.w = fmaf(d2, (float)s0[7], a1.w + b1.w);
        a2.x = fmaf(d2, (float)s1[0], a2.x + b2.x);
        a2.y = fmaf(d2, (float)s1[1], a2.y + b2.y);
        a2.z = fmaf(d2, (float)s1[2], a2.z + b2.z);
        a2.w = fmaf(d2, (float)s1[3], a2.w + b2.w);
        a3.x = fmaf(d2, (float)s1[4], a3.x + b3.x);
        a3.y = fmaf(d2, (float)s1[5], a3.y + b3.y);
        a3.z = fmaf(d2, (float)s1[6], a3.z + b3.z);
        a3.w = fmaf(d2, (float)s1[7], a3.w + b3.w);
        float4 w0 = ((const float4*)lin_w)[q * 4];
        float4 w1 = ((const float4*)lin_w)[q * 4 + 1];
        float4 w2 = ((const float4*)lin_w)[q * 4 + 2];
        float4 w3 = ((const float4*)lin_w)[q * 4 + 3];
        float s = fmaxf(a0.x, 0.f) * w0.x + fmaxf(a0.y, 0.f) * w0.y
                + fmaxf(a0.z, 0.f) * w0.z + fmaxf(a0.w, 0.f) * w0.w
                + fmaxf(a1.x, 0.f) * w1.x + fmaxf(a1.y, 0.f) * w1.y
                + fmaxf(a1.z, 0.f) * w1.z + fmaxf(a1.w, 0.f) * w1.w
                + fmaxf(a2.x, 0.f) * w2.x + fmaxf(a2.y, 0.f) * w2.y
                + fmaxf(a2.z, 0.f) * w2.z + fmaxf(a2.w, 0.f) * w2.w
                + fmaxf(a3.x, 0.f) * w3.x + fmaxf(a3.y, 0.f) * w3.y
                + fmaxf(a3.z, 0.f) * w3.z + fmaxf(a3.w, 0.f) * w3.w;
        s += __shfl_xor(s, 1);
        s += __shfl_xor(s, 2);
        s += __shfl_xor(s, 4);
        if (q == 0) nodeval[w] = s;
    }
}

__device__ __forceinline__ int lower_bound_dev(const int* __restrict__ a, int n, int key) {
    int lo = 0, hi = n;
    while (lo < hi) {
        int mid = (lo + hi) >> 1;
        if (a[mid] < key) lo = mid + 1; else hi = mid;
    }
    return lo;
}

// one block per graph: out[g] = mean(nodeval[lo:hi]) + lin_b  (batch is sorted)
__global__ __launch_bounds__(256) void segreduce_kernel(const float* __restrict__ nodeval,
                                                        const int* __restrict__ batch,
                                                        const float* __restrict__ lin_b,
                                                        float* __restrict__ out, int N) {
    const int g = blockIdx.x;
    const int lo = lower_bound_dev(batch, N, g);
    const int hi = lower_bound_dev(batch, N, g + 1);
    float acc = 0.f;
    for (int n = lo + threadIdx.x; n < hi; n += 256) acc += nodeval[n];
    __shared__ float red[256];
    red[threadIdx.x] = acc;
    __syncthreads();
    for (int s = 128; s > 0; s >>= 1) {
        if (threadIdx.x < s) red[threadIdx.x] += red[threadIdx.x + s];
        __syncthreads();
    }
    if (threadIdx.x == 0) {
        float cnt = (float)(hi - lo);
        out[g] = red[0] / fmaxf(cnt, 1.0f) + lin_b[0];
    }
}

extern "C" void kernel_launch(void* const* d_in, const int* in_sizes, int n_in,
                              void* d_out, int out_size, void* d_ws, size_t ws_size,
                              hipStream_t stream) {
    const float* x     = (const float*)d_in[0];
    const int*   ei    = (const int*)d_in[1];    // [2,E]: rows then cols
    const int*   batch = (const int*)d_in[2];
    const float* W1    = (const float*)d_in[3];
    const float* b1    = (const float*)d_in[4];
    const float* W2    = (const float*)d_in[5];
    const float* b2    = (const float*)d_in[6];
    const float* W3    = (const float*)d_in[7];
    const float* b3    = (const float*)d_in[8];
    const float* lin_w = (const float*)d_in[9];
    const float* lin_b = (const float*)d_in[10];
    float* out = (float*)d_out;

    const int N = in_sizes[0] / 128;
    const int E = in_sizes[1] / 2;
    const int nBlk = (N + 1023) / 1024;
    const int partSize = (N + 7) / 8;            // XCD destination partition
    const int eChunks = (E + 255) / 256;

    // workspace: A16 | H16 | deg | dinv | rowptr | edges(int2) | scan | nodeval | Wfrag
    _Float16* A16    = (_Float16*)d_ws;
    _Float16* H16    = A16 + (size_t)N * 128;
    int*   deg       = (int*)(H16 + (size_t)N * 128);
    float* dinv      = (float*)(deg + N);
    int*   rowptr    = (int*)(dinv + N);
    int2*  edges     = (int2*)(rowptr + N);
    int*   blockSums = (int*)(edges + E);
    int*   blockOffs = blockSums + 256;
    float* nodeval   = (float*)(blockOffs + 256);
    unsigned short* Wfrag = (unsigned short*)(nodeval + N);  // 3 x (hi|lo) x 16384

    // ---- CSR build ----
    hipMemsetAsync(deg, 0, (size_t)N * sizeof(int), stream);
    count_deg_kernel<<<8 * eChunks, 256, 0, stream>>>(ei + E, deg, E, partSize);
    scan1_kernel<<<nBlk, 256, 0, stream>>>(deg, rowptr, dinv, blockSums, N);
    scan2_kernel<<<1, 128, 0, stream>>>(blockSums, blockOffs, nBlk);
    scan3_kernel<<<(N + 255) / 256, 256, 0, stream>>>(rowptr, blockOffs, N);
    fill_kernel<<<8 * eChunks, 256, 0, stream>>>(ei, dinv, rowptr, edges, E, partSize);
    wsplit_kernel<<<192, 256, 0, stream>>>(W1, W2, W3, Wfrag);

    const int gBlocks = (N + 63) / 64;
    const int aBlocks = ((size_t)N * 64 + 255) / 256;

    // layer 1: x @ W1 -> A16 ; agg -> H16 (relu fp16)
    gemm_f32_kernel<<<gBlocks, 256, 0, stream>>>(x, Wfrag, Wfrag + 16384, A16, N);
    agg_kernel<<<aBlocks, 256, 0, stream>>>(rowptr, edges, dinv, A16, b1, H16, N);
    // layer 2: H16 @ W2 -> A16 ; agg -> H16
    gemm_f16_kernel<<<gBlocks, 256, 0, stream>>>(H16, Wfrag + 32768,
                                                 Wfrag + 32768 + 16384, A16, N);
    agg_kernel<<<aBlocks, 256, 0, stream>>>(rowptr, edges, dinv, A16, b2, H16, N);
    // layer 3: H16 @ W3 -> A16 ; head agg + dot -> nodeval
    gemm_f16_kernel<<<gBlocks, 256, 0, stream>>>(H16, Wfrag + 65536,
                                                 Wfrag + 65536 + 16384, A16, N);
    agg_head_kernel<<<aBlocks, 256, 0, stream>>>(rowptr, edges, dinv,
                                                 A16, b3, lin_w, nodeval, N);
    segreduce_kernel<<<64, 256, 0, stream>>>(nodeval, batch, lin_b, out, N);
}